// Round 16
// baseline (248.010 us; speedup 1.0000x reference)
//
#include <hip/hip_runtime.h>
#include <hip/hip_bf16.h>
#include <math.h>

typedef __attribute__((ext_vector_type(8)))  short bf16x8;
typedef __attribute__((ext_vector_type(16))) float f32x16;

__device__ __forceinline__ float bperm(int srcidx, float x) {
    return __int_as_float(__builtin_amdgcn_ds_bpermute(srcidx, __float_as_int(x)));
}
// f32 -> bf16 bits, RNE (manual, bit-deterministic: probes)
__device__ __forceinline__ unsigned f2bfu(float x) {
    unsigned u = __float_as_uint(x);
    return (u + 0x7fffu + ((u >> 16) & 1u)) >> 16;
}
__device__ __forceinline__ float bf2f(unsigned hb) { return __uint_as_float(hb << 16); }
__device__ __forceinline__ unsigned short bfb(float x) {
    __hip_bfloat16 b = __float2bfloat16(x);
    unsigned short u;
    __builtin_memcpy(&u, &b, sizeof(u));
    return u;
}
__device__ __forceinline__ void split(float x, unsigned short& hb, unsigned short& lb) {
    hb = bfb(x);
    float lo = x - bf2f(hb);
    lb = bfb(lo);
}
template <int JM>
__device__ __forceinline__ bf16x8 pick(const unsigned short (&s)[8]) {
    bf16x8 r;
    #pragma unroll
    for (int j = 0; j < 8; ++j) {
        int idx = (JM == 0) ? j : (JM == 1 ? (j ^ 4) : (7 - j));
        r[j] = (short)s[idx];
    }
    return r;
}
template <int JM>
__device__ __forceinline__ bf16x8 pickv(bf16x8 s) {
    bf16x8 r;
    #pragma unroll
    for (int j = 0; j < 8; ++j) {
        int idx = (JM == 0) ? j : (JM == 1 ? (j ^ 4) : (7 - j));
        r[j] = s[idx];
    }
    return r;
}

// logm via Chebyshev deg-11 of log on [1,8], EVEN/ODD split:
//   P(S) = sum c_{2m} T_m(Y) + sum c_{2m+1} Vt_m,  Y = 2S^2 - I,  Vt_m = S*V_m(Y).
// Both T_m(Y) and Vt_m satisfy X_{m+1} = 2*Y*X_m - X_{m-1} (Vt seeds: Vt_{-1}=Vt_0=S).
// Same coefficients as R11-R14 (refcheck'd absmax 0.0); serial LDS roundtrips 10 -> 6,
// independent 6-MFMA chains per super-step 2 -> 4 (2 matrices x {T,Vt}).
// MFMA 32x32x16 bf16 hi/lo split; layout discovered by 3 one-MFMA probes (R10+).
// 64-thread (1-wave) blocks; launch_bounds(64,1) -> VGPR cap 512 (R13 spill lesson).
__global__ __launch_bounds__(64, 1)
void geo_loss_mfma(const float* __restrict__ yhat, const float* __restrict__ y,
                   float* __restrict__ out, int B)
{
    // plane slots per matrix: T-slot holds Y,T2,T3,..; V-slot holds S,Vt1,Vt2,..
    __shared__ unsigned short hT[2][32][40], lT[2][32][40];
    __shared__ unsigned short hV[2][32][40], lV[2][32][40];

    const int lane = threadIdx.x;   // 0..63, one wave per block
    const int c    = lane & 31;
    const int h    = lane >> 5;

    int b = blockIdx.x;
    const float valid = (b < B) ? 1.f : 0.f;
    if (b >= B) b = B - 1;

    const f32x16 zz = {0.f,0.f,0.f,0.f,0.f,0.f,0.f,0.f,0.f,0.f,0.f,0.f,0.f,0.f,0.f,0.f};
    float sent = 0.f;

    // ---- probe 1: relative A/B slot-labeling delta (6 hypotheses) ----
    bf16x8 pa;
    #pragma unroll
    for (int j = 0; j < 8; ++j) pa[j] = (short)f2bfu((float)(8*h + j + 1));
    int sel = -1;
    #pragma unroll
    for (int cand = 0; cand < 6; ++cand) {
        const int hfc = cand & 1, jmc = cand >> 1;
        bf16x8 pb;
        #pragma unroll
        for (int j = 0; j < 8; ++j) {
            int hh = hfc ? (1 - h) : h;
            int jj = (jmc == 0) ? j : (jmc == 1 ? (j ^ 4) : (7 - j));
            float lab = (float)(8*hh + jj + 1);
            pb[j] = (short)f2bfu(lab * lab);
        }
        f32x16 pr = __builtin_amdgcn_mfma_f32_32x32x16_bf16(pa, pb, zz, 0, 0, 0);
        if (sel < 0 && __ballot(pr[0] != 18496.f) == 0ull) sel = cand;
    }
    if (sel < 0) { sent += 1.0e10f; sel = 0; }
    const int hf = sel & 1, jm = sel >> 1;

    // ---- probe 2: C (lane,reg) -> row map ----
    bf16x8 pa2, pb1;
    #pragma unroll
    for (int j = 0; j < 8; ++j) {
        pa2[j] = (short)f2bfu((float)(c + 1));
        pb1[j] = (short)f2bfu(1.f);
    }
    f32x16 r2 = __builtin_amdgcn_mfma_f32_32x32x16_bf16(pa2, pb1, zz, 0, 0, 0);
    int rws[16]; bool ok2 = true;
    #pragma unroll
    for (int i = 0; i < 16; ++i) {
        float q = r2[i] * 0.0625f;
        int ri = (int)(q + 0.5f);
        ok2 = ok2 && (fabsf(q - (float)ri) < 1e-3f) && ri >= 1 && ri <= 32;
        rws[i] = ri - 1;
    }
    if (__ballot(!ok2) != 0ull) {
        sent += 2.0e10f;
        #pragma unroll
        for (int i = 0; i < 16; ++i) rws[i] = (i & 3) + 8*(i >> 2) + 4*h;
    }

    // ---- probe 3: C lane -> col map ----
    f32x16 r3 = __builtin_amdgcn_mfma_f32_32x32x16_bf16(pb1, pa2, zz, 0, 0, 0);
    int colstar;
    {
        float q = r3[0] * 0.0625f;
        int ci = (int)(q + 0.5f);
        bool ok3 = (fabsf(q - (float)ci) < 1e-3f) && ci >= 1 && ci <= 32;
        colstar = ci - 1;
        if (__ballot(!ok3) != 0ull) { sent += 4.0e10f; colstar = c; }
    }

    // quad-contiguity; keep only rq[4] live through the loop
    bool qok = true;
    int rq[4];
    #pragma unroll
    for (int q = 0; q < 4; ++q) {
        rq[q] = rws[4*q];
        qok = qok && ((rws[4*q] & 3) == 0) && (rws[4*q+1] == rws[4*q]+1)
                  && (rws[4*q+2] == rws[4*q]+2) && (rws[4*q+3] == rws[4*q]+3);
    }
    if (__ballot(!qok) != 0ull) {
        sent += 8.0e10f;
        #pragma unroll
        for (int q = 0; q < 4; ++q) rq[q] = 8*q + 4*h;
    }
    if (lane == 0 && sent > 0.f) atomicAdd(out, sent);

    const float INV = 0.2857142857142857f;   // 1/3.5
    const int abase = 8 * (h ^ hf);

    auto packw = [](const unsigned short (&s)[8]) {
        return make_uint4((unsigned)s[0] | ((unsigned)s[1] << 16),
                          (unsigned)s[2] | ((unsigned)s[3] << 16),
                          (unsigned)s[4] | ((unsigned)s[5] << 16),
                          (unsigned)s[6] | ((unsigned)s[7] << 16));
    };

    // ---- stage S for both matrices into V-slot (S == Vt0); build S A-frags ----
    bf16x8 Sh0[2], Sl0[2], Sh1[2], Sl1[2];
    #pragma unroll
    for (int m = 0; m < 2; ++m) {
        const float* Mp = (m == 0 ? yhat : y) + ((size_t)b << 10);
        unsigned short H0[8], L0[8], H1[8], L1[8];
        const float4* p0 = reinterpret_cast<const float4*>(Mp + c*32 + abase);
        float4 q0 = p0[0], q1 = p0[1];
        float f0[8] = {q0.x,q0.y,q0.z,q0.w, q1.x,q1.y,q1.z,q1.w};
        const float4* p1 = reinterpret_cast<const float4*>(Mp + c*32 + 16 + abase);
        float4 q2 = p1[0], q3 = p1[1];
        float f1[8] = {q2.x,q2.y,q2.z,q2.w, q3.x,q3.y,q3.z,q3.w};
        #pragma unroll
        for (int e = 0; e < 8; ++e) {
            int k0 = abase + e, k1 = 16 + abase + e;
            float x0 = (f0[e] - ((k0 == c) ? 4.5f : 0.f)) * INV;
            float x1 = (f1[e] - ((k1 == c) ? 4.5f : 0.f)) * INV;
            split(x0, H0[e], L0[e]);
            split(x1, H1[e], L1[e]);
        }
        *reinterpret_cast<uint4*>(&hV[m][c][abase])      = packw(H0);
        *reinterpret_cast<uint4*>(&lV[m][c][abase])      = packw(L0);
        *reinterpret_cast<uint4*>(&hV[m][c][16 + abase]) = packw(H1);
        *reinterpret_cast<uint4*>(&lV[m][c][16 + abase]) = packw(L1);
        if (jm == 0)      { Sh0[m]=pick<0>(H0); Sl0[m]=pick<0>(L0); Sh1[m]=pick<0>(H1); Sl1[m]=pick<0>(L1); }
        else if (jm == 1) { Sh0[m]=pick<1>(H0); Sl0[m]=pick<1>(L0); Sh1[m]=pick<1>(H1); Sl1[m]=pick<1>(L1); }
        else              { Sh0[m]=pick<2>(H0); Sl0[m]=pick<2>(L0); Sh1[m]=pick<2>(H1); Sl1[m]=pick<2>(L1); }
    }

    // ---- S in C-space (gather, once) ----
    float Scs[2][16];
    #pragma unroll
    for (int m = 0; m < 2; ++m) {
        #pragma unroll
        for (int i = 0; i < 16; ++i)
            Scs[m][i] = bf2f(hV[m][colstar][rws[i]]) + bf2f(lV[m][colstar][rws[i]]);
    }

    // ---- Y = 2*S^2 - I per matrix; Ycs lives in Wtb (= T1 state) ----
    float Wtb[2][16];
    #pragma unroll
    for (int m = 0; m < 2; ++m) {
        bf16x8 Bh0 = *reinterpret_cast<const bf16x8*>(&hV[m][c][8*h]);
        bf16x8 Bl0 = *reinterpret_cast<const bf16x8*>(&lV[m][c][8*h]);
        bf16x8 Bh1 = *reinterpret_cast<const bf16x8*>(&hV[m][c][16 + 8*h]);
        bf16x8 Bl1 = *reinterpret_cast<const bf16x8*>(&lV[m][c][16 + 8*h]);
        f32x16 a = zz;
        a = __builtin_amdgcn_mfma_f32_32x32x16_bf16(Sh0[m], Bh0, a, 0,0,0);
        a = __builtin_amdgcn_mfma_f32_32x32x16_bf16(Sh0[m], Bl0, a, 0,0,0);
        a = __builtin_amdgcn_mfma_f32_32x32x16_bf16(Sl0[m], Bh0, a, 0,0,0);
        a = __builtin_amdgcn_mfma_f32_32x32x16_bf16(Sh1[m], Bh1, a, 0,0,0);
        a = __builtin_amdgcn_mfma_f32_32x32x16_bf16(Sh1[m], Bl1, a, 0,0,0);
        a = __builtin_amdgcn_mfma_f32_32x32x16_bf16(Sl1[m], Bh1, a, 0,0,0);
        #pragma unroll
        for (int i = 0; i < 16; ++i) {
            float dg = (rws[i] == colstar) ? 1.f : 0.f;
            Wtb[m][i] = fmaf(2.f, a[i], -dg);        // Y in C-space
        }
        // store Y into T-slot (quad b64 writes)
        #pragma unroll
        for (int q = 0; q < 4; ++q) {
            int r0 = rq[q];
            unsigned short hb[4], lb[4];
            #pragma unroll
            for (int e = 0; e < 4; ++e) split(Wtb[m][4*q+e], hb[e], lb[e]);
            *reinterpret_cast<uint2*>(&hT[m][colstar][r0]) =
                make_uint2((unsigned)hb[0] | ((unsigned)hb[1] << 16),
                           (unsigned)hb[2] | ((unsigned)hb[3] << 16));
            *reinterpret_cast<uint2*>(&lT[m][colstar][r0]) =
                make_uint2((unsigned)lb[0] | ((unsigned)lb[1] << 16),
                           (unsigned)lb[2] | ((unsigned)lb[3] << 16));
        }
    }

    // ---- Y A-frags (read back T-slot at staging rows + pick) ----
    bf16x8 Yh0[2], Yl0[2], Yh1[2], Yl1[2];
    #pragma unroll
    for (int m = 0; m < 2; ++m) {
        bf16x8 h0 = *reinterpret_cast<const bf16x8*>(&hT[m][c][abase]);
        bf16x8 l0 = *reinterpret_cast<const bf16x8*>(&lT[m][c][abase]);
        bf16x8 h1 = *reinterpret_cast<const bf16x8*>(&hT[m][c][16 + abase]);
        bf16x8 l1 = *reinterpret_cast<const bf16x8*>(&lT[m][c][16 + abase]);
        if (jm == 0)      { Yh0[m]=pickv<0>(h0); Yl0[m]=pickv<0>(l0); Yh1[m]=pickv<0>(h1); Yl1[m]=pickv<0>(l1); }
        else if (jm == 1) { Yh0[m]=pickv<1>(h0); Yl0[m]=pickv<1>(l0); Yh1[m]=pickv<1>(h1); Yl1[m]=pickv<1>(l1); }
        else              { Yh0[m]=pickv<2>(h0); Yl0[m]=pickv<2>(l0); Yh1[m]=pickv<2>(h1); Yl1[m]=pickv<2>(l1); }
    }

    // ---- chain state + P init:  P = c0*I + c1*Vt0(S) + c2*T1(Y) ----
    float Wta[2][16], Wva[2][16], Wvb[2][16], P[2][16];
    #pragma unroll
    for (int m = 0; m < 2; ++m) {
        #pragma unroll
        for (int i = 0; i < 16; ++i) {
            float dg = (rws[i] == colstar) ? 1.f : 0.f;
            Wta[m][i] = dg;                 // T0 = I
            Wva[m][i] = Scs[m][i];          // Vt_{-1} = S
            Wvb[m][i] = Scs[m][i];          // Vt_0 = S
            P[m][i] = fmaf(0.95518452f, Scs[m][i],
                      fmaf(-0.22809412f, Wtb[m][i], 1.2986135f * dg));
        }
    }

    // one chain update: B from plane, 6 MFMAs with Y-frags, recurrence + P accum
    auto CHAIN = [&](float coef, float (&W)[16], float (&Pm)[16],
                     bf16x8 Ah0, bf16x8 Al0, bf16x8 Ah1, bf16x8 Al1,
                     const unsigned short (*sh)[40], const unsigned short (*sl)[40]) {
        bf16x8 Bh0 = *reinterpret_cast<const bf16x8*>(&sh[c][8*h]);
        bf16x8 Bl0 = *reinterpret_cast<const bf16x8*>(&sl[c][8*h]);
        bf16x8 Bh1 = *reinterpret_cast<const bf16x8*>(&sh[c][16 + 8*h]);
        bf16x8 Bl1 = *reinterpret_cast<const bf16x8*>(&sl[c][16 + 8*h]);
        f32x16 a = zz;
        a = __builtin_amdgcn_mfma_f32_32x32x16_bf16(Ah0, Bh0, a, 0,0,0);
        a = __builtin_amdgcn_mfma_f32_32x32x16_bf16(Ah0, Bl0, a, 0,0,0);
        a = __builtin_amdgcn_mfma_f32_32x32x16_bf16(Al0, Bh0, a, 0,0,0);
        a = __builtin_amdgcn_mfma_f32_32x32x16_bf16(Ah1, Bh1, a, 0,0,0);
        a = __builtin_amdgcn_mfma_f32_32x32x16_bf16(Ah1, Bl1, a, 0,0,0);
        a = __builtin_amdgcn_mfma_f32_32x32x16_bf16(Al1, Bh1, a, 0,0,0);
        #pragma unroll
        for (int i = 0; i < 16; ++i) {
            float n = fmaf(2.f, a[i], -W[i]);
            W[i] = n;
            Pm[i] = fmaf(coef, n, Pm[i]);
        }
    };
    auto SAVE = [&](const float (&W)[16],
                    unsigned short (*sh)[40], unsigned short (*sl)[40]) {
        #pragma unroll
        for (int q = 0; q < 4; ++q) {
            int r0 = rq[q];
            unsigned short hb[4], lb[4];
            #pragma unroll
            for (int e = 0; e < 4; ++e) split(W[4*q+e], hb[e], lb[e]);
            *reinterpret_cast<uint2*>(&sh[colstar][r0]) =
                make_uint2((unsigned)hb[0] | ((unsigned)hb[1] << 16),
                           (unsigned)hb[2] | ((unsigned)hb[3] << 16));
            *reinterpret_cast<uint2*>(&sl[colstar][r0]) =
                make_uint2((unsigned)lb[0] | ((unsigned)lb[1] << 16),
                           (unsigned)lb[2] | ((unsigned)lb[3] << 16));
        }
    };

    // super-steps: 4 independent chains each (2 matrices x {T, Vt}); reads before stores
    // SS1: T2 (c4), Vt1 (c3)
    CHAIN(-0.02601347f, Wta[0], P[0], Yh0[0],Yl0[0],Yh1[0],Yl1[0], hT[0], lT[0]);
    CHAIN( 0.07262391f, Wva[0], P[0], Yh0[0],Yl0[0],Yh1[0],Yl1[0], hV[0], lV[0]);
    CHAIN(-0.02601347f, Wta[1], P[1], Yh0[1],Yl0[1],Yh1[1],Yl1[1], hT[1], lT[1]);
    CHAIN( 0.07262391f, Wva[1], P[1], Yh0[1],Yl0[1],Yh1[1],Yl1[1], hV[1], lV[1]);
    SAVE(Wta[0], hT[0], lT[0]); SAVE(Wva[0], hV[0], lV[0]);
    SAVE(Wta[1], hT[1], lT[1]); SAVE(Wva[1], hV[1], lV[1]);
    // SS2: T3 (c6), Vt2 (c5)
    CHAIN(-0.00395568f, Wtb[0], P[0], Yh0[0],Yl0[0],Yh1[0],Yl1[0], hT[0], lT[0]);
    CHAIN( 0.00993906f, Wvb[0], P[0], Yh0[0],Yl0[0],Yh1[0],Yl1[0], hV[0], lV[0]);
    CHAIN(-0.00395568f, Wtb[1], P[1], Yh0[1],Yl0[1],Yh1[1],Yl1[1], hT[1], lT[1]);
    CHAIN( 0.00993906f, Wvb[1], P[1], Yh0[1],Yl0[1],Yh1[1],Yl1[1], hV[1], lV[1]);
    SAVE(Wtb[0], hT[0], lT[0]); SAVE(Wvb[0], hV[0], lV[0]);
    SAVE(Wtb[1], hT[1], lT[1]); SAVE(Wvb[1], hV[1], lV[1]);
    // SS3: T4 (c8), Vt3 (c7)
    CHAIN(-0.00067670f, Wta[0], P[0], Yh0[0],Yl0[0],Yh1[0],Yl1[0], hT[0], lT[0]);
    CHAIN( 0.00161931f, Wva[0], P[0], Yh0[0],Yl0[0],Yh1[0],Yl1[0], hV[0], lV[0]);
    CHAIN(-0.00067670f, Wta[1], P[1], Yh0[1],Yl0[1],Yh1[1],Yl1[1], hT[1], lT[1]);
    CHAIN( 0.00161931f, Wva[1], P[1], Yh0[1],Yl0[1],Yh1[1],Yl1[1], hV[1], lV[1]);
    SAVE(Wta[0], hT[0], lT[0]); SAVE(Wva[0], hV[0], lV[0]);
    SAVE(Wta[1], hT[1], lT[1]); SAVE(Wva[1], hV[1], lV[1]);
    // SS4: T5 (c10, no store - never read again), Vt4 (c9, store)
    CHAIN(-0.00012348f, Wtb[0], P[0], Yh0[0],Yl0[0],Yh1[0],Yl1[0], hT[0], lT[0]);
    CHAIN( 0.00028728f, Wvb[0], P[0], Yh0[0],Yl0[0],Yh1[0],Yl1[0], hV[0], lV[0]);
    CHAIN(-0.00012348f, Wtb[1], P[1], Yh0[1],Yl0[1],Yh1[1],Yl1[1], hT[1], lT[1]);
    CHAIN( 0.00028728f, Wvb[1], P[1], Yh0[1],Yl0[1],Yh1[1],Yl1[1], hV[1], lV[1]);
    SAVE(Wvb[0], hV[0], lV[0]); SAVE(Wvb[1], hV[1], lV[1]);
    // SS5: Vt5 (c11, no store)
    CHAIN( 0.00005361f, Wva[0], P[0], Yh0[0],Yl0[0],Yh1[0],Yl1[0], hV[0], lV[0]);
    CHAIN( 0.00005361f, Wva[1], P[1], Yh0[1],Yl0[1],Yh1[1],Yl1[1], hV[1], lV[1]);

    // ---- loss: ||P_yhat - P_y||_F, wave-reduced; one atomic per block ----
    float s = 0.f;
    #pragma unroll
    for (int i = 0; i < 16; ++i) { float d = P[0][i] - P[1][i]; s = fmaf(d, d, s); }
    #pragma unroll
    for (int m = 32; m >= 1; m >>= 1)
        s += bperm((lane ^ m) << 2, s);
    if (lane == 0) atomicAdd(out, valid * sqrtf(fmaxf(s, 0.f)));
}

extern "C" void kernel_launch(void* const* d_in, const int* in_sizes, int n_in,
                              void* d_out, int out_size, void* d_ws, size_t ws_size,
                              hipStream_t stream)
{
    const float* yhat = (const float*)d_in[0];
    const float* y    = (const float*)d_in[1];
    float* out = (float*)d_out;
    const int B = in_sizes[0] / 1024;   // 32*32 per matrix

    (void)hipMemsetAsync(out, 0, sizeof(float), stream);
    hipLaunchKernelGGL(geo_loss_mfma, dim3(B), dim3(64), 0, stream,
                       yhat, y, out, B);
}

// Round 17
// 136.705 us; speedup vs baseline: 1.8142x; 1.8142x over previous
//
#include <hip/hip_runtime.h>
#include <hip/hip_bf16.h>
#include <math.h>

#define NW 2   // samples per 128-thread block (1 per wave)

typedef __attribute__((ext_vector_type(8)))  short bf16x8;
typedef __attribute__((ext_vector_type(16))) float f32x16;

__device__ __forceinline__ float bperm(int srcidx, float x) {
    return __int_as_float(__builtin_amdgcn_ds_bpermute(srcidx, __float_as_int(x)));
}
// f32 -> bf16 bits, RNE (manual, bit-deterministic: probes)
__device__ __forceinline__ unsigned f2bfu(float x) {
    unsigned u = __float_as_uint(x);
    return (u + 0x7fffu + ((u >> 16) & 1u)) >> 16;
}
__device__ __forceinline__ float bf2f(unsigned hb) { return __uint_as_float(hb << 16); }
__device__ __forceinline__ unsigned short bfb(float x) {
    __hip_bfloat16 b = __float2bfloat16(x);
    unsigned short u;
    __builtin_memcpy(&u, &b, sizeof(u));
    return u;
}
__device__ __forceinline__ void split(float x, unsigned short& hb, unsigned short& lb) {
    hb = bfb(x);
    float lo = x - bf2f(hb);
    lb = bfb(lo);
}
template <int JM>
__device__ __forceinline__ bf16x8 pick(const unsigned short (&s)[8]) {
    bf16x8 r;
    #pragma unroll
    for (int j = 0; j < 8; ++j) {
        int idx = (JM == 0) ? j : (JM == 1 ? (j ^ 4) : (7 - j));
        r[j] = (short)s[idx];
    }
    return r;
}
// two ds_read_b64 -> one bf16x8 (stride-36 planes: 8B aligned, 2-way conflicts = free)
__device__ __forceinline__ bf16x8 rd8(const unsigned short* p) {
    uint2 a = *reinterpret_cast<const uint2*>(p);
    uint2 b = *reinterpret_cast<const uint2*>(p + 4);
    union { unsigned u[4]; bf16x8 v; } r;
    r.u[0] = a.x; r.u[1] = a.y; r.u[2] = b.x; r.u[3] = b.y;
    return r.v;
}

// logm via Chebyshev deg-11 of log on [1,8]: S=(M-4.5I)/3.5, T_{k+1}=2*S*T_k-T_{k-1}.
// A-operand S: full hi/lo bf16 split in REGISTERS (precision carrier).
// B-operand T_k: bf16-ONLY LDS plane (stride 36 u16: b64 ops, 2-way conflicts=free).
// Error budget: B-rounding 2^-9 enters P via sum c_k*k*2^-8 ~ 2e-3/elem -> total
// loss error ~13 of threshold 1228 (output bf16 quantum ~512). Layout discovered
// by 3 one-MFMA probes (proven R10-R14, absmax 0.0). R14 structure (133us) kept:
// dual-chain (both matrices) per wave, 10 serial STEPs, launch_bounds(128,1).
__global__ __launch_bounds__(128, 1)
void geo_loss_mfma(const float* __restrict__ yhat, const float* __restrict__ y,
                   float* __restrict__ out, int B)
{
    __shared__ unsigned short TA[NW][32][36];   // chain-1 (yhat) T_k plane, bf16
    __shared__ unsigned short TB[NW][32][36];   // chain-2 (y)    T_k plane, bf16
    __shared__ float bl[NW];

    const int t    = threadIdx.x;
    const int w    = t >> 6;
    const int lane = t & 63;
    const int c    = lane & 31;
    const int h    = lane >> 5;

    int b = blockIdx.x * NW + w;
    const float valid = (b < B) ? 1.f : 0.f;
    if (b >= B) b = B - 1;

    const f32x16 zz = {0.f,0.f,0.f,0.f,0.f,0.f,0.f,0.f,0.f,0.f,0.f,0.f,0.f,0.f,0.f,0.f};
    float sent = 0.f;

    // ---- probe 1: relative A/B slot-labeling delta (6 hypotheses) ----
    bf16x8 pa;
    #pragma unroll
    for (int j = 0; j < 8; ++j) pa[j] = (short)f2bfu((float)(8*h + j + 1));
    int sel = -1;
    #pragma unroll
    for (int cand = 0; cand < 6; ++cand) {
        const int hfc = cand & 1, jmc = cand >> 1;
        bf16x8 pb;
        #pragma unroll
        for (int j = 0; j < 8; ++j) {
            int hh = hfc ? (1 - h) : h;
            int jj = (jmc == 0) ? j : (jmc == 1 ? (j ^ 4) : (7 - j));
            float lab = (float)(8*hh + jj + 1);
            pb[j] = (short)f2bfu(lab * lab);
        }
        f32x16 pr = __builtin_amdgcn_mfma_f32_32x32x16_bf16(pa, pb, zz, 0, 0, 0);
        if (sel < 0 && __ballot(pr[0] != 18496.f) == 0ull) sel = cand;
    }
    if (sel < 0) { sent += 1.0e10f; sel = 0; }
    const int hf = sel & 1, jm = sel >> 1;

    // ---- probe 2: C (lane,reg) -> row map (init-only) ----
    bf16x8 pa2, pb1;
    #pragma unroll
    for (int j = 0; j < 8; ++j) {
        pa2[j] = (short)f2bfu((float)(c + 1));
        pb1[j] = (short)f2bfu(1.f);
    }
    f32x16 r2 = __builtin_amdgcn_mfma_f32_32x32x16_bf16(pa2, pb1, zz, 0, 0, 0);
    int rws[16]; bool ok2 = true;
    #pragma unroll
    for (int i = 0; i < 16; ++i) {
        float q = r2[i] * 0.0625f;
        int ri = (int)(q + 0.5f);
        ok2 = ok2 && (fabsf(q - (float)ri) < 1e-3f) && ri >= 1 && ri <= 32;
        rws[i] = ri - 1;
    }
    if (__ballot(!ok2) != 0ull) {
        sent += 2.0e10f;
        #pragma unroll
        for (int i = 0; i < 16; ++i) rws[i] = (i & 3) + 8*(i >> 2) + 4*h;
    }

    // ---- probe 3: C lane -> col map ----
    f32x16 r3 = __builtin_amdgcn_mfma_f32_32x32x16_bf16(pb1, pa2, zz, 0, 0, 0);
    int colstar;
    {
        float q = r3[0] * 0.0625f;
        int ci = (int)(q + 0.5f);
        bool ok3 = (fabsf(q - (float)ci) < 1e-3f) && ci >= 1 && ci <= 32;
        colstar = ci - 1;
        if (__ballot(!ok3) != 0ull) { sent += 4.0e10f; colstar = c; }
    }

    // quad-contiguity; keep only rq[4] live through the loop
    bool qok = true;
    int rq[4];
    #pragma unroll
    for (int q = 0; q < 4; ++q) {
        rq[q] = rws[4*q];
        qok = qok && ((rws[4*q] & 3) == 0) && (rws[4*q+1] == rws[4*q]+1)
                  && (rws[4*q+2] == rws[4*q]+2) && (rws[4*q+3] == rws[4*q]+3);
    }
    if (__ballot(!qok) != 0ull) {
        sent += 8.0e10f;
        #pragma unroll
        for (int q = 0; q < 4; ++q) rq[q] = 8*q + 4*h;
    }
    if (lane == 0 && sent > 0.f) atomicAdd(out, sent);

    const float INV = 0.2857142857142857f;   // 1/3.5
    const int abase = 8 * (h ^ hf);

    // ---- load S rows; A-frags hi/lo in regs; stage bf16 S (=T1) to planes ----
    bf16x8 A1h0, A1l0, A1h1, A1l1, A2h0, A2l0, A2h1, A2l1;
    #pragma unroll
    for (int m = 0; m < 2; ++m) {
        const float* Mp = (m == 0 ? yhat : y) + ((size_t)b << 10);
        unsigned short H0[8], L0[8], H1[8], L1[8];
        const float4* p0 = reinterpret_cast<const float4*>(Mp + c*32 + abase);
        float4 q0 = p0[0], q1 = p0[1];
        float f0[8] = {q0.x,q0.y,q0.z,q0.w, q1.x,q1.y,q1.z,q1.w};
        const float4* p1 = reinterpret_cast<const float4*>(Mp + c*32 + 16 + abase);
        float4 q2 = p1[0], q3 = p1[1];
        float f1[8] = {q2.x,q2.y,q2.z,q2.w, q3.x,q3.y,q3.z,q3.w};
        #pragma unroll
        for (int e = 0; e < 8; ++e) {
            int k0 = abase + e, k1 = 16 + abase + e;
            float x0 = (f0[e] - ((k0 == c) ? 4.5f : 0.f)) * INV;
            float x1 = (f1[e] - ((k1 == c) ? 4.5f : 0.f)) * INV;
            split(x0, H0[e], L0[e]);
            split(x1, H1[e], L1[e]);
        }
        unsigned short (*pl)[36] = (m == 0) ? TA[w] : TB[w];
        // b64 stores (stride-36 planes)
        *reinterpret_cast<uint2*>(&pl[c][abase]) =
            make_uint2((unsigned)H0[0] | ((unsigned)H0[1] << 16),
                       (unsigned)H0[2] | ((unsigned)H0[3] << 16));
        *reinterpret_cast<uint2*>(&pl[c][abase + 4]) =
            make_uint2((unsigned)H0[4] | ((unsigned)H0[5] << 16),
                       (unsigned)H0[6] | ((unsigned)H0[7] << 16));
        *reinterpret_cast<uint2*>(&pl[c][16 + abase]) =
            make_uint2((unsigned)H1[0] | ((unsigned)H1[1] << 16),
                       (unsigned)H1[2] | ((unsigned)H1[3] << 16));
        *reinterpret_cast<uint2*>(&pl[c][16 + abase + 4]) =
            make_uint2((unsigned)H1[4] | ((unsigned)H1[5] << 16),
                       (unsigned)H1[6] | ((unsigned)H1[7] << 16));
        bf16x8 ah0, al0, ah1, al1;
        if (jm == 0)      { ah0=pick<0>(H0); al0=pick<0>(L0); ah1=pick<0>(H1); al1=pick<0>(L1); }
        else if (jm == 1) { ah0=pick<1>(H0); al0=pick<1>(L0); ah1=pick<1>(H1); al1=pick<1>(L1); }
        else              { ah0=pick<2>(H0); al0=pick<2>(L0); ah1=pick<2>(H1); al1=pick<2>(L1); }
        if (m == 0) { A1h0=ah0; A1l0=al0; A1h1=ah1; A1l1=al1; }
        else        { A2h0=ah0; A2l0=al0; A2h1=ah1; A2l1=al1; }
    }

    // ---- init recurrence state (T1 = S from plane, bf16 precision) ----
    float U1[16], V1[16], P1[16], U2[16], V2[16], P2[16];
    #pragma unroll
    for (int i = 0; i < 16; ++i) {
        float dg = (rws[i] == colstar) ? 1.f : 0.f;
        float tv1 = bf2f(TA[w][colstar][rws[i]]);
        float tv2 = bf2f(TB[w][colstar][rws[i]]);
        V1[i] = tv1; V2[i] = tv2; U1[i] = dg; U2[i] = dg;
        P1[i] = fmaf(0.95518452f, tv1, 1.2986135f * dg);
        P2[i] = fmaf(0.95518452f, tv2, 1.2986135f * dg);
    }

    // dual-chain Chebyshev step: 4 MFMAs per matrix (A hi/lo x B bf16), b64 LDS ops
    auto STEP = [&](float coef, float (&W1)[16], float (&W2)[16], bool dostore) {
        bf16x8 B10 = rd8(&TA[w][c][8*h]);
        bf16x8 B11 = rd8(&TA[w][c][16 + 8*h]);
        bf16x8 B20 = rd8(&TB[w][c][8*h]);
        bf16x8 B21 = rd8(&TB[w][c][16 + 8*h]);
        f32x16 a1 = zz, a2 = zz;
        a1 = __builtin_amdgcn_mfma_f32_32x32x16_bf16(A1h0, B10, a1, 0,0,0);
        a2 = __builtin_amdgcn_mfma_f32_32x32x16_bf16(A2h0, B20, a2, 0,0,0);
        a1 = __builtin_amdgcn_mfma_f32_32x32x16_bf16(A1l0, B10, a1, 0,0,0);
        a2 = __builtin_amdgcn_mfma_f32_32x32x16_bf16(A2l0, B20, a2, 0,0,0);
        a1 = __builtin_amdgcn_mfma_f32_32x32x16_bf16(A1h1, B11, a1, 0,0,0);
        a2 = __builtin_amdgcn_mfma_f32_32x32x16_bf16(A2h1, B21, a2, 0,0,0);
        a1 = __builtin_amdgcn_mfma_f32_32x32x16_bf16(A1l1, B11, a1, 0,0,0);
        a2 = __builtin_amdgcn_mfma_f32_32x32x16_bf16(A2l1, B21, a2, 0,0,0);
        #pragma unroll
        for (int i = 0; i < 16; ++i) {
            float n1 = fmaf(2.f, a1[i], -W1[i]);
            float n2 = fmaf(2.f, a2[i], -W2[i]);
            W1[i] = n1; W2[i] = n2;
            P1[i] = fmaf(coef, n1, P1[i]);
            P2[i] = fmaf(coef, n2, P2[i]);
        }
        if (dostore) {
            #pragma unroll
            for (int q = 0; q < 4; ++q) {
                int r0 = rq[q];
                unsigned short b1[4], b2[4];
                #pragma unroll
                for (int e = 0; e < 4; ++e) {
                    b1[e] = bfb(W1[4*q+e]);
                    b2[e] = bfb(W2[4*q+e]);
                }
                *reinterpret_cast<uint2*>(&TA[w][colstar][r0]) =
                    make_uint2((unsigned)b1[0] | ((unsigned)b1[1] << 16),
                               (unsigned)b1[2] | ((unsigned)b1[3] << 16));
                *reinterpret_cast<uint2*>(&TB[w][colstar][r0]) =
                    make_uint2((unsigned)b2[0] | ((unsigned)b2[1] << 16),
                               (unsigned)b2[2] | ((unsigned)b2[3] << 16));
            }
        }
    };

    STEP(-0.22809412f, U1, U2, true);    // T2
    STEP( 0.07262391f, V1, V2, true);    // T3
    STEP(-0.02601347f, U1, U2, true);    // T4
    STEP( 0.00993906f, V1, V2, true);    // T5
    STEP(-0.00395568f, U1, U2, true);    // T6
    STEP( 0.00161931f, V1, V2, true);    // T7
    STEP(-0.00067670f, U1, U2, true);    // T8
    STEP( 0.00028728f, V1, V2, true);    // T9
    STEP(-0.00012348f, U1, U2, true);    // T10
    STEP( 0.00005361f, V1, V2, false);   // T11 (T12 term dropped: <=2.4e-5)

    float s = 0.f;
    #pragma unroll
    for (int i = 0; i < 16; ++i) { float d = P1[i] - P2[i]; s = fmaf(d, d, s); }
    #pragma unroll
    for (int m = 32; m >= 1; m >>= 1)
        s += bperm((lane ^ m) << 2, s);
    if (lane == 0) bl[w] = valid * sqrtf(fmaxf(s, 0.f));

    __syncthreads();
    if (t == 0) {
        float sum = 0.f;
        #pragma unroll
        for (int i = 0; i < NW; ++i) sum += bl[i];
        atomicAdd(out, sum);
    }
}

extern "C" void kernel_launch(void* const* d_in, const int* in_sizes, int n_in,
                              void* d_out, int out_size, void* d_ws, size_t ws_size,
                              hipStream_t stream)
{
    const float* yhat = (const float*)d_in[0];
    const float* y    = (const float*)d_in[1];
    float* out = (float*)d_out;
    const int B = in_sizes[0] / 1024;   // 32*32 per matrix

    (void)hipMemsetAsync(out, 0, sizeof(float), stream);
    const int grid = (B + NW - 1) / NW;
    hipLaunchKernelGGL(geo_loss_mfma, dim3(grid), dim3(128), 0, stream,
                       yhat, y, out, B);
}